// Round 2
// baseline (531.797 us; speedup 1.0000x reference)
//
#include <hip/hip_runtime.h>
#include <hip/hip_bf16.h>
#include <cstdint>
#include <cstddef>

// Problem constants (from reference setup_inputs)
constexpr int BROWS = 4096;    // batch rows
constexpr int MREAL = 12893;   // prototypes
constexpr int MPAD  = 12928;   // 101*128, zero-padded rows in workspace
constexpr int KDIM  = 2048;
constexpr int NT    = KDIM / 64;   // 32 K-tiles of BK=64

typedef __attribute__((ext_vector_type(8))) short short8;   // 8 x bf16 (4 VGPRs)
typedef __attribute__((ext_vector_type(4))) float f32x4;    // MFMA accumulator

// Async global->LDS, 16B per lane. LDS dest = wave-uniform base + lane*16.
__device__ __forceinline__ void gld_lds16(const void* g, void* l) {
  __builtin_amdgcn_global_load_lds((__attribute__((address_space(1))) const void*)g,
                                   (__attribute__((address_space(3))) void*)l,
                                   16, 0, 0);
}

// ---------------------------------------------------------------------------
// Row-wise L2 normalize fp32 -> bf16, one WAVE per row (no LDS, no barrier).
// Global wave id = row index over [x rows | p rows]; p pad rows zero-filled.
// 8 float4 loads/lane issued back-to-back for MLP; butterfly shfl reduce.
// ---------------------------------------------------------------------------
__global__ void l2norm_fused(const float* __restrict__ x,
                             const float* __restrict__ p,
                             __hip_bfloat16* __restrict__ xn,
                             __hip_bfloat16* __restrict__ pn) {
  const int wid  = (int)((blockIdx.x * (unsigned)blockDim.x + threadIdx.x) >> 6);
  const int lane = threadIdx.x & 63;

  const float* irow;
  __hip_bfloat16* orow;
  if (wid < BROWS) {
    irow = x + (size_t)wid * KDIM;
    orow = xn + (size_t)wid * KDIM;
  } else {
    const int row = wid - BROWS;
    orow = pn + (size_t)row * KDIM;
    if (row >= MREAL) {           // zero-fill pad rows (wave-uniform branch)
      ushort4 z = {0, 0, 0, 0};
      #pragma unroll
      for (int j = 0; j < 8; ++j)
        reinterpret_cast<ushort4*>(orow)[lane + 64 * j] = z;
      return;
    }
    irow = p + (size_t)row * KDIM;
  }

  const float4* iv = reinterpret_cast<const float4*>(irow);
  float4 v[8];
  #pragma unroll
  for (int j = 0; j < 8; ++j) v[j] = iv[lane + 64 * j];

  float ss = 0.f;
  #pragma unroll
  for (int j = 0; j < 8; ++j)
    ss += v[j].x * v[j].x + v[j].y * v[j].y + v[j].z * v[j].z + v[j].w * v[j].w;

  #pragma unroll
  for (int off = 1; off < 64; off <<= 1) ss += __shfl_xor(ss, off);

  const float inv = 1.0f / fmaxf(sqrtf(ss), 1e-12f);   // F.normalize semantics

  #pragma unroll
  for (int j = 0; j < 8; ++j) {
    union { ushort4 u; __hip_bfloat16 h[4]; } o;
    o.h[0] = __float2bfloat16(v[j].x * inv);
    o.h[1] = __float2bfloat16(v[j].y * inv);
    o.h[2] = __float2bfloat16(v[j].z * inv);
    o.h[3] = __float2bfloat16(v[j].w * inv);
    reinterpret_cast<ushort4*>(orow)[lane + 64 * j] = o.u;
  }
}

// ---------------------------------------------------------------------------
// C[b,m] = -|s| * sqrt(max(2 - 2*dot(xn[b], pn[m]), 0))
// 256x256 tile, BK=64, 8 waves (2M x 4N), 8-phase counted-vmcnt schedule.
// R2 change: deeper staggered staging (issue-to-wait distance 5-6 phases,
// vmcnt(6) like the m201 template) using per-region liveness:
//   buf.B dead after its Q0 phase; buf.A rows{0,2}(Q0Q1) after Q1;
//   buf.A rows{1,3}(Q2Q3) after Q3.
// Steady-state schedule (iter i, T0=2i, T1=2i+1; stage T0+2->buf0, T1+2->buf1):
//   ph1 buf0.Q0 | issue A(T1)->buf1 rows{1,3}
//   ph2 buf0.Q1 | issue B(T0+2)->buf0 rows{0,1}
//   ph3 buf0.Q2 | issue B(T0+2) rows{2,3} + A(T0+2) rows{0,2}
//   ph4 buf0.Q3 | vmcnt(6)  -> retires all 8 loads of buf1 (tile T1)
//   ph5 buf1.Q0 | issue A(T0+2)->buf0 rows{1,3}
//   ph6 buf1.Q1 | issue B(T1+2)->buf1 rows{0,1}
//   ph7 buf1.Q2 | issue B(T1+2) rows{2,3} + A(T1+2) rows{0,2}
//   ph8 buf1.Q3 | vmcnt(6)  -> retires all 8 loads of buf0 (tile T0+2)
// Ledger (outstanding): enter ph1 = 6; +2,+2,+4 -> 14; ph4 wait 6 retires
// prev-ph6(2)+prev-ph7(4)+ph1(2) = buf1's 8. Symmetric for ph8.
// ---------------------------------------------------------------------------
__global__ __launch_bounds__(512, 2)
void gemm_dist(const __hip_bfloat16* __restrict__ A,
               const __hip_bfloat16* __restrict__ P,
               const float* __restrict__ scale,
               float* __restrict__ out) {
  __shared__ __hip_bfloat16 lds[65536];           // 128 KiB
  __hip_bfloat16* const sA = lds;                 // [2][256][64]
  __hip_bfloat16* const sB = lds + 32768;         // [2][256][64]

  const int t    = threadIdx.x;       // 0..511
  const int lane = t & 63;
  const int wv   = t >> 6;            // 0..7
  const int wm   = wv >> 2;           // 0..1 : wave row (128 rows each)
  const int wn   = wv & 3;            // 0..3 : wave col (64 cols each)

  // T1: bijective XCD swizzle. nwg = 816 = 8 * 102.
  const int bid = blockIdx.x;
  const int swz = (bid & 7) * 102 + (bid >> 3);
  const int bm0 = (swz / 51) * 256;   // M tile (16 tiles)
  const int bn0 = (swz % 51) * 256;   // N tile (51 tiles, covers 13056)

  // ---- staging map: thread covers LDS row srow(+64r), physical slot sp ----
  const int srow = t >> 3;            // 0..63
  const int sp   = t & 7;             // physical 16B slot
  const int ssl  = sp ^ (srow & 7);   // inverse-swizzled global slot
  const __hip_bfloat16* aSrc[4];
  const __hip_bfloat16* bSrc[4];
  int sOff[4];                        // LDS element offset (linear: == t*16 B)
  #pragma unroll
  for (int r = 0; r < 4; ++r) {
    aSrc[r] = A + (size_t)(bm0 + r*64 + srow) * KDIM + ssl*8;
    int br = bn0 + r*64 + srow;
    br = br < MPAD ? br : (MPAD - 1);          // clamp: OOB cols masked in epi
    bSrc[r] = P + (size_t)br * KDIM + ssl*8;
    sOff[r] = (r*64 + srow)*64 + sp*8;
  }

  // ---- fragment map (A-layout: row = lane&15, k-slot = lane>>4; swizzled) ----
  const int l15 = lane & 15, hi = lane >> 4;
  const int pk0 = ( hi      ^ (lane & 7)) * 8;   // phys slot for kk=0 (elems)
  const int pk1 = ((hi + 4) ^ (lane & 7)) * 8;   // phys slot for kk=1
  const int aBase = (wm*128 + l15) * 64;
  const int bBase = (wn*64  + l15) * 64;

  f32x4 acc[8][4];
  #pragma unroll
  for (int i = 0; i < 8; ++i)
    #pragma unroll
    for (int j = 0; j < 4; ++j) acc[i][j] = f32x4{0.f, 0.f, 0.f, 0.f};

// Two loads: A rows Ra,Rb of K-tile T into buf BUF (LDS linear, src swizzled).
#define STG_AP(BUF, Ra, Rb, T) do { const int kt_ = ((T)*64) & (KDIM-1);      \
    gld_lds16(aSrc[(Ra)] + kt_, sA + (BUF)*16384 + sOff[(Ra)]);               \
    gld_lds16(aSrc[(Rb)] + kt_, sA + (BUF)*16384 + sOff[(Rb)]); } while(0)
#define STG_BP(BUF, Ra, Rb, T) do { const int kt_ = ((T)*64) & (KDIM-1);      \
    gld_lds16(bSrc[(Ra)] + kt_, sB + (BUF)*16384 + sOff[(Ra)]);               \
    gld_lds16(bSrc[(Rb)] + kt_, sB + (BUF)*16384 + sOff[(Rb)]); } while(0)

  // Prologue: buf0 <- tile 0 (8 loads); buf1 <- tile 1 partial (6 loads;
  // A rows{1,3} deferred to ph1 per steady-state). vmcnt(6) = buf0 landed.
  STG_BP(0, 0, 1, 0); STG_BP(0, 2, 3, 0);
  STG_AP(0, 0, 2, 0); STG_AP(0, 1, 3, 0);
  STG_BP(1, 0, 1, 1); STG_BP(1, 2, 3, 1);
  STG_AP(1, 0, 2, 1);
  asm volatile("s_waitcnt vmcnt(6)" ::: "memory");
  __builtin_amdgcn_s_barrier();

  short8 bfr[4][2];   // B fragments cached across the 4 quadrant phases

// Phase: {ds-read frags | issue staging} -> [lgkm(8) if 12 reads] -> barrier
//        -> lgkmcnt(0) -> setprio(1) 16xMFMA setprio(0) -> [vmcnt(6)] -> barrier.
#define PHASE(BUF, Q, READB, STG, VM) do {                                    \
    asm volatile("" ::: "memory");                                            \
    const __hip_bfloat16* sAb = sA + (BUF)*16384;                             \
    const __hip_bfloat16* sBb = sB + (BUF)*16384;                             \
    if (READB) {                                                              \
      _Pragma("unroll")                                                       \
      for (int j = 0; j < 4; ++j) {                                           \
        bfr[j][0] = *reinterpret_cast<const short8*>(sBb + bBase + j*1024 + pk0); \
        bfr[j][1] = *reinterpret_cast<const short8*>(sBb + bBase + j*1024 + pk1); \
      }                                                                       \
    }                                                                         \
    const short8 a00 = *reinterpret_cast<const short8*>(sAb + aBase + (Q)*2048 + pk0); \
    const short8 a01 = *reinterpret_cast<const short8*>(sAb + aBase + (Q)*2048 + pk1); \
    const short8 a10 = *reinterpret_cast<const short8*>(sAb + aBase + (Q)*2048 + 1024 + pk0); \
    const short8 a11 = *reinterpret_cast<const short8*>(sAb + aBase + (Q)*2048 + 1024 + pk1); \
    STG;                                                                      \
    if (READB) asm volatile("s_waitcnt lgkmcnt(8)" ::: "memory");             \
    __builtin_amdgcn_s_barrier();                                             \
    asm volatile("s_waitcnt lgkmcnt(0)" ::: "memory");                        \
    __builtin_amdgcn_s_setprio(1);                                            \
    _Pragma("unroll")                                                         \
    for (int j = 0; j < 4; ++j) {                                             \
      acc[2*(Q)  ][j] = __builtin_amdgcn_mfma_f32_16x16x32_bf16(a00, bfr[j][0], acc[2*(Q)  ][j], 0, 0, 0); \
      acc[2*(Q)  ][j] = __builtin_amdgcn_mfma_f32_16x16x32_bf16(a01, bfr[j][1], acc[2*(Q)  ][j], 0, 0, 0); \
      acc[2*(Q)+1][j] = __builtin_amdgcn_mfma_f32_16x16x32_bf16(a10, bfr[j][0], acc[2*(Q)+1][j], 0, 0, 0); \
      acc[2*(Q)+1][j] = __builtin_amdgcn_mfma_f32_16x16x32_bf16(a11, bfr[j][1], acc[2*(Q)+1][j], 0, 0, 0); \
    }                                                                         \
    __builtin_amdgcn_s_setprio(0);                                            \
    if (VM) asm volatile("s_waitcnt vmcnt(6)" ::: "memory");                  \
    __builtin_amdgcn_s_barrier();                                             \
  } while (0)

  for (int it = 0; it < NT/2; ++it) {
    const int T0 = 2*it, T1 = 2*it + 1;
    PHASE(0, 0, true , STG_AP(1, 1, 3, T1),                            false);
    PHASE(0, 1, false, STG_BP(0, 0, 1, (T0+2)),                        false);
    PHASE(0, 2, false, { STG_BP(0, 2, 3, (T0+2)); STG_AP(0, 0, 2, (T0+2)); }, false);
    PHASE(0, 3, false, { /* no staging */ },                           true );
    PHASE(1, 0, true , STG_AP(0, 1, 3, (T0+2)),                        false);
    PHASE(1, 1, false, STG_BP(1, 0, 1, (T1+2)),                        false);
    PHASE(1, 2, false, { STG_BP(1, 2, 3, (T1+2)); STG_AP(1, 0, 2, (T1+2)); }, false);
    PHASE(1, 3, false, { /* no staging */ },                           true );
  }

  // Epilogue: C/D layout col = lane&15, row = (lane>>4)*4 + reg  [m89/m91]
  const float s = fabsf(scale[0]);
  const int colb = bn0 + wn*64 + l15;
  #pragma unroll
  for (int i = 0; i < 8; ++i) {
    const int rowb = bm0 + wm*128 + i*16 + hi*4;
    #pragma unroll
    for (int j = 0; j < 4; ++j) {
      const int col = colb + j*16;
      if (col < MREAL) {
        #pragma unroll
        for (int r = 0; r < 4; ++r) {
          float d2 = fmaxf(2.0f - 2.0f*acc[i][j][r], 0.0f);
          out[(size_t)(rowb + r)*MREAL + col] = -s * __builtin_sqrtf(d2);
        }
      }
    }
  }
  // Drain tail DMAs (6 in-flight LDS writes) before wave exit.
  asm volatile("s_waitcnt vmcnt(0)" ::: "memory");
}

#undef PHASE
#undef STG_AP
#undef STG_BP

// ---------------------------------------------------------------------------
extern "C" void kernel_launch(void* const* d_in, const int* in_sizes, int n_in,
                              void* d_out, int out_size, void* d_ws, size_t ws_size,
                              hipStream_t stream) {
  const float* x = (const float*)d_in[0];          // [4096, 2048] fp32
  const float* p = (const float*)d_in[1];          // [12893, 2048] fp32
  const float* s = (const float*)d_in[2];          // [1] fp32
  float* out = (float*)d_out;                      // [4096, 12893] fp32

  // Workspace: xn bf16 [4096][2048] then pn bf16 [12928][2048]  (~66.5 MB)
  __hip_bfloat16* xn = (__hip_bfloat16*)d_ws;
  __hip_bfloat16* pn = xn + (size_t)BROWS * KDIM;

  // One wave per row: (4096 + 12928) rows * 64 lanes / 256 threads = 4256 blocks
  l2norm_fused<<<(BROWS + MPAD) / 4, 256, 0, stream>>>(x, p, xn, pn);

  // 16 M-tiles x 51 N-tiles = 816 blocks (matches the XCD-swizzle constant).
  gemm_dist<<<816, 512, 0, stream>>>(xn, pn, s, out);
}

// Round 3
// 526.346 us; speedup vs baseline: 1.0104x; 1.0104x over previous
//
#include <hip/hip_runtime.h>
#include <hip/hip_bf16.h>
#include <cstdint>
#include <cstddef>

// Problem constants (from reference setup_inputs)
constexpr int BROWS = 4096;    // batch rows
constexpr int MREAL = 12893;   // prototypes
constexpr int MPAD  = 12928;   // 101*128, zero-padded rows in workspace
constexpr int KDIM  = 2048;
constexpr int NT    = KDIM / 64;   // 32 K-tiles of BK=64

typedef __attribute__((ext_vector_type(8))) short short8;   // 8 x bf16 (4 VGPRs)
typedef __attribute__((ext_vector_type(4))) float f32x4;    // MFMA accumulator

// Async global->LDS, 16B per lane. LDS dest = wave-uniform base + lane*16.
__device__ __forceinline__ void gld_lds16(const void* g, void* l) {
  __builtin_amdgcn_global_load_lds((__attribute__((address_space(1))) const void*)g,
                                   (__attribute__((address_space(3))) void*)l,
                                   16, 0, 0);
}

// ---------------------------------------------------------------------------
// Row-wise L2 normalize fp32 -> bf16, one WAVE per row (no LDS, no barrier).
// ---------------------------------------------------------------------------
__global__ void l2norm_fused(const float* __restrict__ x,
                             const float* __restrict__ p,
                             __hip_bfloat16* __restrict__ xn,
                             __hip_bfloat16* __restrict__ pn) {
  const int wid  = (int)((blockIdx.x * (unsigned)blockDim.x + threadIdx.x) >> 6);
  const int lane = threadIdx.x & 63;

  const float* irow;
  __hip_bfloat16* orow;
  if (wid < BROWS) {
    irow = x + (size_t)wid * KDIM;
    orow = xn + (size_t)wid * KDIM;
  } else {
    const int row = wid - BROWS;
    orow = pn + (size_t)row * KDIM;
    if (row >= MREAL) {           // zero-fill pad rows (wave-uniform branch)
      ushort4 z = {0, 0, 0, 0};
      #pragma unroll
      for (int j = 0; j < 8; ++j)
        reinterpret_cast<ushort4*>(orow)[lane + 64 * j] = z;
      return;
    }
    irow = p + (size_t)row * KDIM;
  }

  const float4* iv = reinterpret_cast<const float4*>(irow);
  float4 v[8];
  #pragma unroll
  for (int j = 0; j < 8; ++j) v[j] = iv[lane + 64 * j];

  float ss = 0.f;
  #pragma unroll
  for (int j = 0; j < 8; ++j)
    ss += v[j].x * v[j].x + v[j].y * v[j].y + v[j].z * v[j].z + v[j].w * v[j].w;

  #pragma unroll
  for (int off = 1; off < 64; off <<= 1) ss += __shfl_xor(ss, off);

  const float inv = 1.0f / fmaxf(sqrtf(ss), 1e-12f);   // F.normalize semantics

  #pragma unroll
  for (int j = 0; j < 8; ++j) {
    union { ushort4 u; __hip_bfloat16 h[4]; } o;
    o.h[0] = __float2bfloat16(v[j].x * inv);
    o.h[1] = __float2bfloat16(v[j].y * inv);
    o.h[2] = __float2bfloat16(v[j].z * inv);
    o.h[3] = __float2bfloat16(v[j].w * inv);
    reinterpret_cast<ushort4*>(orow)[lane + 64 * j] = o.u;
  }
}

// ---------------------------------------------------------------------------
// C[b,m] = -|s| * sqrt(max(2 - 2*dot(xn[b], pn[m]), 0))
// 256x256 tile, BK=64, 8 waves (2M x 4N), 8-phase schedule, TEMPLATE-EXACT
// stagger (R3): one half-tile (2 gld_lds) staged in EVERY phase, vmcnt(6)
// only at ph4/ph8. Half-tiles: B-h0 = B rows 0-127 (regions 0,1); B-h1 =
// rows 128-255 (2,3); A-h0 = regions {0,2} (Q0Q1 rows for both wave-groups);
// A-h1 = regions {1,3} (Q2Q3 rows).
//
// Steady state (iter: ph1-4 compute buf0/tile T0, ph5-8 compute buf1/T1):
//   ph1 buf0.Q0 | A-h1(T1)->buf1     (buf1 Q2Q3 last read prev-ph8)
//   ph2 buf0.Q1 | B-h0(T0+2)->buf0   (buf0.B last read ph1)
//   ph3 buf0.Q2 | B-h1(T0+2)->buf0
//   ph4 buf0.Q3 | A-h0(T0+2)->buf0   (buf0 Q0Q1 last read ph2); vmcnt(6)
//                 -> retires {prev-ph6,prev-ph7,prev-ph8,ph1} = buf1(T1) done
//   ph5 buf1.Q0 | A-h1(T0+2)->buf0   (buf0 Q2Q3 last read ph4)
//   ph6 buf1.Q1 | B-h0(T1+2)->buf1   (buf1.B last read ph5)
//   ph7 buf1.Q2 | B-h1(T1+2)->buf1
//   ph8 buf1.Q3 | A-h0(T1+2)->buf1   (buf1 Q0Q1 last read ph6); vmcnt(6)
//                 -> retires {ph2,ph3,ph4,ph5} = buf0(T0+2) done
// In-flight: 6-14 loads; issue-to-wait distance 3-6 phases (m218/m201 regime).
// ---------------------------------------------------------------------------
__global__ __launch_bounds__(512, 2)
void gemm_dist(const __hip_bfloat16* __restrict__ A,
               const __hip_bfloat16* __restrict__ P,
               const float* __restrict__ scale,
               float* __restrict__ out) {
  __shared__ __hip_bfloat16 lds[65536];           // 128 KiB
  __hip_bfloat16* const sA = lds;                 // [2][256][64]
  __hip_bfloat16* const sB = lds + 32768;         // [2][256][64]

  const int t    = threadIdx.x;       // 0..511
  const int lane = t & 63;
  const int wv   = t >> 6;            // 0..7
  const int wm   = wv >> 2;           // 0..1 : wave row (128 rows each)
  const int wn   = wv & 3;            // 0..3 : wave col (64 cols each)

  // T1: bijective XCD swizzle. nwg = 816 = 8 * 102.
  const int bid = blockIdx.x;
  const int swz = (bid & 7) * 102 + (bid >> 3);
  const int bm0 = (swz / 51) * 256;   // M tile (16 tiles)
  const int bn0 = (swz % 51) * 256;   // N tile (51 tiles, covers 13056)

  // ---- staging map: thread covers LDS row srow(+64r), physical slot sp ----
  const int srow = t >> 3;            // 0..63
  const int sp   = t & 7;             // physical 16B slot
  const int ssl  = sp ^ (srow & 7);   // inverse-swizzled global slot
  const __hip_bfloat16* aSrc[4];
  const __hip_bfloat16* bSrc[4];
  int sOff[4];                        // LDS element offset (linear: == t*16 B)
  #pragma unroll
  for (int r = 0; r < 4; ++r) {
    aSrc[r] = A + (size_t)(bm0 + r*64 + srow) * KDIM + ssl*8;
    int br = bn0 + r*64 + srow;
    br = br < MPAD ? br : (MPAD - 1);          // clamp: OOB cols masked in epi
    bSrc[r] = P + (size_t)br * KDIM + ssl*8;
    sOff[r] = (r*64 + srow)*64 + sp*8;
  }

  // ---- fragment map (A-layout: row = lane&15, k-slot = lane>>4; swizzled) ----
  const int l15 = lane & 15, hi = lane >> 4;
  const int pk0 = ( hi      ^ (lane & 7)) * 8;   // phys slot for kk=0 (elems)
  const int pk1 = ((hi + 4) ^ (lane & 7)) * 8;   // phys slot for kk=1
  const int aBase = (wm*128 + l15) * 64;
  const int bBase = (wn*64  + l15) * 64;

  f32x4 acc[8][4];
  #pragma unroll
  for (int i = 0; i < 8; ++i)
    #pragma unroll
    for (int j = 0; j < 4; ++j) acc[i][j] = f32x4{0.f, 0.f, 0.f, 0.f};

// Two loads: A regions Ra,Rb of K-tile T into buf BUF (LDS linear, src swizzled).
#define STG_AP(BUF, Ra, Rb, T) do { const int kt_ = ((T)*64) & (KDIM-1);      \
    gld_lds16(aSrc[(Ra)] + kt_, sA + (BUF)*16384 + sOff[(Ra)]);               \
    gld_lds16(aSrc[(Rb)] + kt_, sA + (BUF)*16384 + sOff[(Rb)]); } while(0)
#define STG_BP(BUF, Ra, Rb, T) do { const int kt_ = ((T)*64) & (KDIM-1);      \
    gld_lds16(bSrc[(Ra)] + kt_, sB + (BUF)*16384 + sOff[(Ra)]);               \
    gld_lds16(bSrc[(Rb)] + kt_, sB + (BUF)*16384 + sOff[(Rb)]); } while(0)

  // Prologue: buf0 <- tile 0 full (8 loads), then buf1 <- tile 1 partial
  // in steady-state order {B-h0, B-h1, A-h0} (6 loads); A-h1(T1) comes at ph1.
  // vmcnt(6) retires the oldest 8 = buf0 complete.
  STG_BP(0, 0, 1, 0); STG_BP(0, 2, 3, 0);
  STG_AP(0, 0, 2, 0); STG_AP(0, 1, 3, 0);
  STG_BP(1, 0, 1, 1); STG_BP(1, 2, 3, 1);
  STG_AP(1, 0, 2, 1);
  asm volatile("s_waitcnt vmcnt(6)" ::: "memory");
  __builtin_amdgcn_s_barrier();

  short8 bfr[4][2];   // B fragments cached across the 4 quadrant phases

// Phase: {ds-read frags | issue 1 half-tile} -> barrier -> lgkmcnt(0) ->
//        setprio(1) 16xMFMA setprio(0) -> [vmcnt(6)] -> barrier.
// Leading empty asm = fence so LDS reads don't hoist above prev barrier.
#define PHASE(BUF, Q, READB, STG, VM) do {                                    \
    asm volatile("" ::: "memory");                                            \
    const __hip_bfloat16* sAb = sA + (BUF)*16384;                             \
    const __hip_bfloat16* sBb = sB + (BUF)*16384;                             \
    if (READB) {                                                              \
      _Pragma("unroll")                                                       \
      for (int j = 0; j < 4; ++j) {                                           \
        bfr[j][0] = *reinterpret_cast<const short8*>(sBb + bBase + j*1024 + pk0); \
        bfr[j][1] = *reinterpret_cast<const short8*>(sBb + bBase + j*1024 + pk1); \
      }                                                                       \
    }                                                                         \
    const short8 a00 = *reinterpret_cast<const short8*>(sAb + aBase + (Q)*2048 + pk0); \
    const short8 a01 = *reinterpret_cast<const short8*>(sAb + aBase + (Q)*2048 + pk1); \
    const short8 a10 = *reinterpret_cast<const short8*>(sAb + aBase + (Q)*2048 + 1024 + pk0); \
    const short8 a11 = *reinterpret_cast<const short8*>(sAb + aBase + (Q)*2048 + 1024 + pk1); \
    STG;                                                                      \
    __builtin_amdgcn_s_barrier();                                             \
    asm volatile("s_waitcnt lgkmcnt(0)" ::: "memory");                        \
    __builtin_amdgcn_s_setprio(1);                                            \
    _Pragma("unroll")                                                         \
    for (int j = 0; j < 4; ++j) {                                             \
      acc[2*(Q)  ][j] = __builtin_amdgcn_mfma_f32_16x16x32_bf16(a00, bfr[j][0], acc[2*(Q)  ][j], 0, 0, 0); \
      acc[2*(Q)  ][j] = __builtin_amdgcn_mfma_f32_16x16x32_bf16(a01, bfr[j][1], acc[2*(Q)  ][j], 0, 0, 0); \
      acc[2*(Q)+1][j] = __builtin_amdgcn_mfma_f32_16x16x32_bf16(a10, bfr[j][0], acc[2*(Q)+1][j], 0, 0, 0); \
      acc[2*(Q)+1][j] = __builtin_amdgcn_mfma_f32_16x16x32_bf16(a11, bfr[j][1], acc[2*(Q)+1][j], 0, 0, 0); \
    }                                                                         \
    __builtin_amdgcn_s_setprio(0);                                            \
    if (VM) asm volatile("s_waitcnt vmcnt(6)" ::: "memory");                  \
    __builtin_amdgcn_s_barrier();                                             \
  } while (0)

  for (int it = 0; it < NT/2; ++it) {
    const int T0 = 2*it, T1 = 2*it + 1;
    PHASE(0, 0, true , STG_AP(1, 1, 3, T1),     false);
    PHASE(0, 1, false, STG_BP(0, 0, 1, (T0+2)), false);
    PHASE(0, 2, false, STG_BP(0, 2, 3, (T0+2)), false);
    PHASE(0, 3, false, STG_AP(0, 0, 2, (T0+2)), true );
    PHASE(1, 0, true , STG_AP(0, 1, 3, (T0+2)), false);
    PHASE(1, 1, false, STG_BP(1, 0, 1, (T1+2)), false);
    PHASE(1, 2, false, STG_BP(1, 2, 3, (T1+2)), false);
    PHASE(1, 3, false, STG_AP(1, 0, 2, (T1+2)), true );
  }

  // Epilogue: C/D layout col = lane&15, row = (lane>>4)*4 + reg  [m89/m91]
  const float s = fabsf(scale[0]);
  const int colb = bn0 + wn*64 + l15;
  #pragma unroll
  for (int i = 0; i < 8; ++i) {
    const int rowb = bm0 + wm*128 + i*16 + hi*4;
    #pragma unroll
    for (int j = 0; j < 4; ++j) {
      const int col = colb + j*16;
      if (col < MREAL) {
        #pragma unroll
        for (int r = 0; r < 4; ++r) {
          float d2 = fmaxf(2.0f - 2.0f*acc[i][j][r], 0.0f);
          out[(size_t)(rowb + r)*MREAL + col] = -s * __builtin_sqrtf(d2);
        }
      }
    }
  }
  // Drain tail DMAs (6 in-flight wrap-around LDS writes) before wave exit.
  asm volatile("s_waitcnt vmcnt(0)" ::: "memory");
}

#undef PHASE
#undef STG_AP
#undef STG_BP

// ---------------------------------------------------------------------------
extern "C" void kernel_launch(void* const* d_in, const int* in_sizes, int n_in,
                              void* d_out, int out_size, void* d_ws, size_t ws_size,
                              hipStream_t stream) {
  const float* x = (const float*)d_in[0];          // [4096, 2048] fp32
  const float* p = (const float*)d_in[1];          // [12893, 2048] fp32
  const float* s = (const float*)d_in[2];          // [1] fp32
  float* out = (float*)d_out;                      // [4096, 12893] fp32

  // Workspace: xn bf16 [4096][2048] then pn bf16 [12928][2048]  (~66.5 MB)
  __hip_bfloat16* xn = (__hip_bfloat16*)d_ws;
  __hip_bfloat16* pn = xn + (size_t)BROWS * KDIM;

  // One wave per row: (4096 + 12928) rows * 64 lanes / 256 threads = 4256 blocks
  l2norm_fused<<<(BROWS + MPAD) / 4, 256, 0, stream>>>(x, p, xn, pn);

  // 16 M-tiles x 51 N-tiles = 816 blocks (matches the XCD-swizzle constant).
  gemm_dist<<<816, 512, 0, stream>>>(xn, pn, s, out);
}

// Round 4
// 526.175 us; speedup vs baseline: 1.0107x; 1.0003x over previous
//
#include <hip/hip_runtime.h>
#include <hip/hip_bf16.h>
#include <cstdint>
#include <cstddef>

// Problem constants (from reference setup_inputs)
constexpr int BROWS = 4096;    // batch rows
constexpr int MREAL = 12893;   // prototypes
constexpr int MPAD  = 12928;   // 101*128, zero-padded rows in workspace
constexpr int KDIM  = 2048;
constexpr int NT    = KDIM / 64;   // 32 K-tiles of BK=64

typedef __attribute__((ext_vector_type(8))) short short8;   // 8 x bf16 (4 VGPRs)
typedef __attribute__((ext_vector_type(4))) float f32x4;    // MFMA accumulator

// Async global->LDS, 16B per lane. LDS dest = wave-uniform base + lane*16.
__device__ __forceinline__ void gld_lds16(const void* g, void* l) {
  __builtin_amdgcn_global_load_lds((__attribute__((address_space(1))) const void*)g,
                                   (__attribute__((address_space(3))) void*)l,
                                   16, 0, 0);
}

// ---------------------------------------------------------------------------
// Row-wise L2 normalize fp32 -> bf16, one WAVE per row (no LDS, no barrier).
// ---------------------------------------------------------------------------
__global__ void l2norm_fused(const float* __restrict__ x,
                             const float* __restrict__ p,
                             __hip_bfloat16* __restrict__ xn,
                             __hip_bfloat16* __restrict__ pn) {
  const int wid  = (int)((blockIdx.x * (unsigned)blockDim.x + threadIdx.x) >> 6);
  const int lane = threadIdx.x & 63;

  const float* irow;
  __hip_bfloat16* orow;
  if (wid < BROWS) {
    irow = x + (size_t)wid * KDIM;
    orow = xn + (size_t)wid * KDIM;
  } else {
    const int row = wid - BROWS;
    orow = pn + (size_t)row * KDIM;
    if (row >= MREAL) {           // zero-fill pad rows (wave-uniform branch)
      ushort4 z = {0, 0, 0, 0};
      #pragma unroll
      for (int j = 0; j < 8; ++j)
        reinterpret_cast<ushort4*>(orow)[lane + 64 * j] = z;
      return;
    }
    irow = p + (size_t)row * KDIM;
  }

  const float4* iv = reinterpret_cast<const float4*>(irow);
  float4 v[8];
  #pragma unroll
  for (int j = 0; j < 8; ++j) v[j] = iv[lane + 64 * j];

  float ss = 0.f;
  #pragma unroll
  for (int j = 0; j < 8; ++j)
    ss += v[j].x * v[j].x + v[j].y * v[j].y + v[j].z * v[j].z + v[j].w * v[j].w;

  #pragma unroll
  for (int off = 1; off < 64; off <<= 1) ss += __shfl_xor(ss, off);

  const float inv = 1.0f / fmaxf(sqrtf(ss), 1e-12f);   // F.normalize semantics

  #pragma unroll
  for (int j = 0; j < 8; ++j) {
    union { ushort4 u; __hip_bfloat16 h[4]; } o;
    o.h[0] = __float2bfloat16(v[j].x * inv);
    o.h[1] = __float2bfloat16(v[j].y * inv);
    o.h[2] = __float2bfloat16(v[j].z * inv);
    o.h[3] = __float2bfloat16(v[j].w * inv);
    reinterpret_cast<ushort4*>(orow)[lane + 64 * j] = o.u;
  }
}

// ---------------------------------------------------------------------------
// C[b,m] = -|s| * sqrt(max(2 - 2*dot(xn[b], pn[m]), 0))
// 256x256 tile, BK=64, 8 waves (2M x 4N), 8-phase schedule, R3 stagger ledger
// (one half-tile staged per phase, vmcnt(6) at ph4/ph8).
// R4 changes (phase critical-chain cuts; ledger & stagger UNCHANGED):
//  1. Single barrier per phase (dropped pre-MFMA barrier + explicit lgkm(0)).
//     Safety: each phase's ds_reads are consumed by its own MFMAs, so the
//     compiler's waitcnt forces completion before the wave reaches the
//     trailing barrier; stages issue only after the previous barrier, so a
//     region staged in phase k was read in phase <=k-1 by ALL waves. Wave
//     drift stays <1 phase -> R3 vmcnt ledger still valid.
//  2. kk-outer MFMA order: 8 independent MFMAs then 8 (dep distance 8,
//     ~39 cyc > MFMA latency) instead of dependent pairs at distance 1.
//  3. Intra-XCD row-pair block order: XCD c owns M-rows {2c,2c+1} x all N,
//     column-major, so concurrent blocks pair-share B panels via L2 and A
//     (2 MB/XCD) stays L2-resident across all generations.
// ---------------------------------------------------------------------------
__global__ __launch_bounds__(512, 2)
void gemm_dist(const __hip_bfloat16* __restrict__ A,
               const __hip_bfloat16* __restrict__ P,
               const float* __restrict__ scale,
               float* __restrict__ out) {
  __shared__ __hip_bfloat16 lds[65536];           // 128 KiB
  __hip_bfloat16* const sA = lds;                 // [2][256][64]
  __hip_bfloat16* const sB = lds + 32768;         // [2][256][64]

  const int t    = threadIdx.x;       // 0..511
  const int lane = t & 63;
  const int wv   = t >> 6;            // 0..7
  const int wm   = wv >> 2;           // 0..1 : wave row (128 rows each)
  const int wn   = wv & 3;            // 0..3 : wave col (64 cols each)

  // XCD-aware mapping: XCD = bid&7 owns M-tile rows {2*xcd, 2*xcd+1} x 51 N,
  // enumerated column-major so concurrent blocks pair on the same B panel.
  const int bid = blockIdx.x;
  const int xcd = bid & 7;
  const int l   = bid >> 3;           // 0..101
  const int bm0 = ((xcd << 1) + (l & 1)) * 256;  // M tile row
  const int bn0 = (l >> 1) * 256;                // N tile col (0..50)

  // ---- staging map: thread covers LDS row srow(+64r), physical slot sp ----
  const int srow = t >> 3;            // 0..63
  const int sp   = t & 7;             // physical 16B slot
  const int ssl  = sp ^ (srow & 7);   // inverse-swizzled global slot
  const __hip_bfloat16* aSrc[4];
  const __hip_bfloat16* bSrc[4];
  int sOff[4];                        // LDS element offset (linear: == t*16 B)
  #pragma unroll
  for (int r = 0; r < 4; ++r) {
    aSrc[r] = A + (size_t)(bm0 + r*64 + srow) * KDIM + ssl*8;
    int br = bn0 + r*64 + srow;
    br = br < MPAD ? br : (MPAD - 1);          // clamp: OOB cols masked in epi
    bSrc[r] = P + (size_t)br * KDIM + ssl*8;
    sOff[r] = (r*64 + srow)*64 + sp*8;
  }

  // ---- fragment map (A-layout: row = lane&15, k-slot = lane>>4; swizzled) ----
  const int l15 = lane & 15, hi = lane >> 4;
  const int pk0 = ( hi      ^ (lane & 7)) * 8;   // phys slot for kk=0 (elems)
  const int pk1 = ((hi + 4) ^ (lane & 7)) * 8;   // phys slot for kk=1
  const int aBase = (wm*128 + l15) * 64;
  const int bBase = (wn*64  + l15) * 64;

  f32x4 acc[8][4];
  #pragma unroll
  for (int i = 0; i < 8; ++i)
    #pragma unroll
    for (int j = 0; j < 4; ++j) acc[i][j] = f32x4{0.f, 0.f, 0.f, 0.f};

// Two loads: A regions Ra,Rb of K-tile T into buf BUF (LDS linear, src swizzled).
#define STG_AP(BUF, Ra, Rb, T) do { const int kt_ = ((T)*64) & (KDIM-1);      \
    gld_lds16(aSrc[(Ra)] + kt_, sA + (BUF)*16384 + sOff[(Ra)]);               \
    gld_lds16(aSrc[(Rb)] + kt_, sA + (BUF)*16384 + sOff[(Rb)]); } while(0)
#define STG_BP(BUF, Ra, Rb, T) do { const int kt_ = ((T)*64) & (KDIM-1);      \
    gld_lds16(bSrc[(Ra)] + kt_, sB + (BUF)*16384 + sOff[(Ra)]);               \
    gld_lds16(bSrc[(Rb)] + kt_, sB + (BUF)*16384 + sOff[(Rb)]); } while(0)

  // Prologue: buf0 <- tile 0 full (8 loads), then buf1 <- tile 1 partial
  // in steady-state order {B-h0, B-h1, A-h0} (6 loads); A-h1(T1) comes at ph1.
  // vmcnt(6) retires the oldest 8 = buf0 complete.
  STG_BP(0, 0, 1, 0); STG_BP(0, 2, 3, 0);
  STG_AP(0, 0, 2, 0); STG_AP(0, 1, 3, 0);
  STG_BP(1, 0, 1, 1); STG_BP(1, 2, 3, 1);
  STG_AP(1, 0, 2, 1);
  asm volatile("s_waitcnt vmcnt(6)" ::: "memory");
  __builtin_amdgcn_s_barrier();

  short8 bfr[4][2];   // B fragments cached across the 4 quadrant phases

// Phase: {ds-read frags | issue 1 half-tile} -> setprio(1) 16xMFMA (kk-outer)
//        setprio(0) -> [vmcnt(6)] -> barrier.   (single barrier per phase)
// Leading empty asm = fence so LDS reads don't hoist above prev barrier.
// Compiler inserts fine-grained lgkmcnt before each MFMA's operand use.
#define PHASE(BUF, Q, READB, STG, VM) do {                                    \
    asm volatile("" ::: "memory");                                            \
    const __hip_bfloat16* sAb = sA + (BUF)*16384;                             \
    const __hip_bfloat16* sBb = sB + (BUF)*16384;                             \
    if (READB) {                                                              \
      _Pragma("unroll")                                                       \
      for (int j = 0; j < 4; ++j) {                                           \
        bfr[j][0] = *reinterpret_cast<const short8*>(sBb + bBase + j*1024 + pk0); \
        bfr[j][1] = *reinterpret_cast<const short8*>(sBb + bBase + j*1024 + pk1); \
      }                                                                       \
    }                                                                         \
    const short8 aI0K0 = *reinterpret_cast<const short8*>(sAb + aBase + (Q)*2048 + pk0); \
    const short8 aI0K1 = *reinterpret_cast<const short8*>(sAb + aBase + (Q)*2048 + pk1); \
    const short8 aI1K0 = *reinterpret_cast<const short8*>(sAb + aBase + (Q)*2048 + 1024 + pk0); \
    const short8 aI1K1 = *reinterpret_cast<const short8*>(sAb + aBase + (Q)*2048 + 1024 + pk1); \
    STG;                                                                      \
    __builtin_amdgcn_s_setprio(1);                                            \
    _Pragma("unroll")                                                         \
    for (int j = 0; j < 4; ++j)                                               \
      acc[2*(Q)  ][j] = __builtin_amdgcn_mfma_f32_16x16x32_bf16(aI0K0, bfr[j][0], acc[2*(Q)  ][j], 0, 0, 0); \
    _Pragma("unroll")                                                         \
    for (int j = 0; j < 4; ++j)                                               \
      acc[2*(Q)+1][j] = __builtin_amdgcn_mfma_f32_16x16x32_bf16(aI1K0, bfr[j][0], acc[2*(Q)+1][j], 0, 0, 0); \
    _Pragma("unroll")                                                         \
    for (int j = 0; j < 4; ++j)                                               \
      acc[2*(Q)  ][j] = __builtin_amdgcn_mfma_f32_16x16x32_bf16(aI0K1, bfr[j][1], acc[2*(Q)  ][j], 0, 0, 0); \
    _Pragma("unroll")                                                         \
    for (int j = 0; j < 4; ++j)                                               \
      acc[2*(Q)+1][j] = __builtin_amdgcn_mfma_f32_16x16x32_bf16(aI1K1, bfr[j][1], acc[2*(Q)+1][j], 0, 0, 0); \
    __builtin_amdgcn_s_setprio(0);                                            \
    if (VM) asm volatile("s_waitcnt vmcnt(6)" ::: "memory");                  \
    __builtin_amdgcn_s_barrier();                                             \
  } while (0)

  for (int it = 0; it < NT/2; ++it) {
    const int T0 = 2*it, T1 = 2*it + 1;
    PHASE(0, 0, true , STG_AP(1, 1, 3, T1),     false);
    PHASE(0, 1, false, STG_BP(0, 0, 1, (T0+2)), false);
    PHASE(0, 2, false, STG_BP(0, 2, 3, (T0+2)), false);
    PHASE(0, 3, false, STG_AP(0, 0, 2, (T0+2)), true );
    PHASE(1, 0, true , STG_AP(0, 1, 3, (T0+2)), false);
    PHASE(1, 1, false, STG_BP(1, 0, 1, (T1+2)), false);
    PHASE(1, 2, false, STG_BP(1, 2, 3, (T1+2)), false);
    PHASE(1, 3, false, STG_AP(1, 0, 2, (T1+2)), true );
  }

  // Epilogue: C/D layout col = lane&15, row = (lane>>4)*4 + reg  [m89/m91]
  const float s = fabsf(scale[0]);
  const int colb = bn0 + wn*64 + l15;
  #pragma unroll
  for (int i = 0; i < 8; ++i) {
    const int rowb = bm0 + wm*128 + i*16 + hi*4;
    #pragma unroll
    for (int j = 0; j < 4; ++j) {
      const int col = colb + j*16;
      if (col < MREAL) {
        #pragma unroll
        for (int r = 0; r < 4; ++r) {
          float d2 = fmaxf(2.0f - 2.0f*acc[i][j][r], 0.0f);
          out[(size_t)(rowb + r)*MREAL + col] = -s * __builtin_sqrtf(d2);
        }
      }
    }
  }
  // Drain tail DMAs (6 in-flight wrap-around LDS writes) before wave exit.
  asm volatile("s_waitcnt vmcnt(0)" ::: "memory");
}

#undef PHASE
#undef STG_AP
#undef STG_BP

// ---------------------------------------------------------------------------
extern "C" void kernel_launch(void* const* d_in, const int* in_sizes, int n_in,
                              void* d_out, int out_size, void* d_ws, size_t ws_size,
                              hipStream_t stream) {
  const float* x = (const float*)d_in[0];          // [4096, 2048] fp32
  const float* p = (const float*)d_in[1];          // [12893, 2048] fp32
  const float* s = (const float*)d_in[2];          // [1] fp32
  float* out = (float*)d_out;                      // [4096, 12893] fp32

  // Workspace: xn bf16 [4096][2048] then pn bf16 [12928][2048]  (~66.5 MB)
  __hip_bfloat16* xn = (__hip_bfloat16*)d_ws;
  __hip_bfloat16* pn = xn + (size_t)BROWS * KDIM;

  // One wave per row: (4096 + 12928) rows * 64 lanes / 256 threads = 4256 blocks
  l2norm_fused<<<(BROWS + MPAD) / 4, 256, 0, stream>>>(x, p, xn, pn);

  // 16 M-tiles x 51 N-tiles = 816 blocks.
  gemm_dist<<<816, 512, 0, stream>>>(xn, pn, s, out);
}